// Round 6
// baseline (242.426 us; speedup 1.0000x reference)
//
#include <hip/hip_runtime.h>

// Problem constants
constexpr int BATCH = 4;
constexpr int SEQQ  = 1024;
constexpr int SEQK  = 2048;
constexpr int DIM   = 1024;
constexpr int NH    = 16;
constexpr int DH    = 64;
constexpr int RQ    = BATCH * SEQQ;          // 4096 q rows
constexpr int RK    = BATCH * SEQK;          // 8192 k rows (== v rows)
constexpr int RTOT  = RQ + 2 * RK;           // 20480
constexpr int BH    = BATCH * NH;            // 64
constexpr int NSLC  = 8;                     // s_kernel K-slices
constexpr float LN_EPS = 1e-5f;

typedef _Float16 f16;
typedef __attribute__((ext_vector_type(8))) _Float16 f16x8;
typedef __attribute__((ext_vector_type(4))) float f32x4;

__device__ __forceinline__ void async16(const void* g, void* l) {
  __builtin_amdgcn_global_load_lds(
      (const __attribute__((address_space(1))) void*)g,
      (__attribute__((address_space(3))) void*)l, 16, 0, 0);
}

// ---------------------------------------------------------------------------
// K0: fused prep. Blocks [0, RTOT/4): LayerNorm -> fp16 (one wave per row).
// Blocks [RTOT/4, +2048): 32x32-tile transpose+f16 of W_in / W_out.
// ---------------------------------------------------------------------------
__global__ void __launch_bounds__(256) prep_kernel(
    const float* __restrict__ q, const float* __restrict__ k,
    const float* __restrict__ v, const float* __restrict__ gamma,
    const float* __restrict__ beta, f16* __restrict__ a_h,
    const float* __restrict__ W0, const float* __restrict__ W1,
    f16* __restrict__ T0, f16* __restrict__ T1) {
  __shared__ float tile[32][33];
  if (blockIdx.x < RTOT / 4) {
    const int row = blockIdx.x * 4 + (threadIdx.x >> 6);
    const int lane = threadIdx.x & 63;
    const float* src;
    if (row < RQ)            src = q + (size_t)row * DIM;
    else if (row < RQ + RK)  src = k + (size_t)(row - RQ) * DIM;
    else                     src = v + (size_t)(row - RQ - RK) * DIM;
    float4 x[4];
    float s = 0.f, s2 = 0.f;
#pragma unroll
    for (int c = 0; c < 4; c++) {
      x[c] = ((const float4*)src)[c * 64 + lane];
      s  += x[c].x + x[c].y + x[c].z + x[c].w;
      s2 += x[c].x * x[c].x + x[c].y * x[c].y + x[c].z * x[c].z + x[c].w * x[c].w;
    }
#pragma unroll
    for (int off = 1; off < 64; off <<= 1) {
      s  += __shfl_xor(s, off);
      s2 += __shfl_xor(s2, off);
    }
    const float mu = s / DIM;
    const float rs = rsqrtf(s2 / DIM - mu * mu + LN_EPS);
#pragma unroll
    for (int c = 0; c < 4; c++) {
      float4 g = ((const float4*)gamma)[c * 64 + lane];
      float4 b = ((const float4*)beta)[c * 64 + lane];
      union { f16 h[4]; uint2 u; } o;
      o.h[0] = (f16)((x[c].x - mu) * rs * g.x + b.x);
      o.h[1] = (f16)((x[c].y - mu) * rs * g.y + b.y);
      o.h[2] = (f16)((x[c].z - mu) * rs * g.z + b.z);
      o.h[3] = (f16)((x[c].w - mu) * rs * g.w + b.w);
      ((uint2*)(a_h + (size_t)row * DIM))[c * 64 + lane] = o.u;
    }
  } else {
    const int bid = blockIdx.x - RTOT / 4;  // 0..2047
    const int z = bid >> 10;
    const int rem = bid & 1023;
    const float* W = z ? W1 : W0;
    f16* T = z ? T1 : T0;
    const int k0 = (rem >> 5) * 32, n0 = (rem & 31) * 32;
    const int tx = threadIdx.x & 31, ty = threadIdx.x >> 5;
#pragma unroll
    for (int i = 0; i < 4; i++)
      tile[ty + 8 * i][tx] = W[(size_t)(k0 + ty + 8 * i) * DIM + n0 + tx];
    __syncthreads();
#pragma unroll
    for (int i = 0; i < 4; i++)
      T[(size_t)(n0 + ty + 8 * i) * DIM + k0 + tx] = (f16)tile[tx][ty + 8 * i];
  }
}

// ---------------------------------------------------------------------------
// MFMA fp16 GEMM, C[M x 1024] = A[M x 1024] * Bt^T, Bt N-major [1024][1024].
// MT x 128 tile, BK=64 as two BK=32 sub-buffers, one barrier pair per 64-K.
// LDS chunk-rotation swizzle keeps fragment ds_read_b128 conflict-free.
// NORMS (MT=128, proj only): each wave's 64-col quadrant is one head —
// butterfly-reduce sum(x^2) per row, scale acc by rsqrt before f16 store
// (q/k rows pre-normalized; v rows untouched).
// PERB (final GEMM): Bt indexed per batch (row0>>10).
// ---------------------------------------------------------------------------
template <int MT, bool OUT_F16, bool NORMS, bool BIAS, bool PERB>
__global__ void __launch_bounds__(256) mfma_gemm(
    const f16* __restrict__ A, const f16* __restrict__ Bt,
    void* __restrict__ Cout, const float* __restrict__ bias) {
  constexpr int JT = (MT == 128) ? 4 : 2;
  __shared__ f16 As[2][MT * 32];
  __shared__ f16 Bs[2][128 * 32];
  const int t = threadIdx.x;
  const int wid = t >> 6;
  const int lane = t & 63;
  const int row0 = blockIdx.x * MT;
  const int col0 = blockIdx.y * 128;
  const int wm = (MT == 128) ? (wid >> 1) * 64 : 0;
  const int wn = (MT == 128) ? (wid & 1) * 64 : wid * 32;

  const f16* BtB = PERB ? Bt + (size_t)(row0 >> 10) * DIM * DIM : Bt;

  // staging pointers (chunk-rotation swizzle on the fetch column)
  const int rB = 32 * wid + (lane >> 2);
  const int qB = ((lane & 3) - ((rB >> 1) & 3)) & 3;
  const f16* gB = BtB + (size_t)(col0 + rB) * DIM + qB * 8;
  f16* lB0 = Bs[0] + 32 * wid * 32;
  f16* lB1 = Bs[1] + 32 * wid * 32;
  const int rA = (MT == 128 ? 32 : 16) * wid + (lane >> 2);
  const int qA = ((lane & 3) - ((rA >> 1) & 3)) & 3;
  const f16* gA = A + (size_t)(row0 + rA) * DIM + qA * 8;
  f16* lA0 = As[0] + (MT == 128 ? 32 : 16) * wid * 32;
  f16* lA1 = As[1] + (MT == 128 ? 32 : 16) * wid * 32;

  f32x4 acc[4][JT];
#pragma unroll
  for (int i = 0; i < 4; i++)
#pragma unroll
    for (int j = 0; j < JT; j++) acc[i][j] = (f32x4){0.f, 0.f, 0.f, 0.f};

  const int mrow = lane & 15;
  const int kq_p = (((lane >> 4) + ((lane >> 1) & 3)) & 3) * 8;

  for (int kt = 0; kt < DIM / 64; ++kt) {
    if (kt) __syncthreads();
    const int ko = kt * 64;
    async16(gA + ko,      lA0);
    if (MT == 128) async16(gA + ko + 16 * DIM, lA0 + 512);
    async16(gB + ko,      lB0);
    async16(gB + ko + 16 * DIM, lB0 + 512);
    async16(gA + ko + 32, lA1);
    if (MT == 128) async16(gA + ko + 32 + 16 * DIM, lA1 + 512);
    async16(gB + ko + 32, lB1);
    async16(gB + ko + 32 + 16 * DIM, lB1 + 512);
    __syncthreads();

#pragma unroll
    for (int h = 0; h < 2; ++h) {
      f16x8 af[4], bf[JT];
#pragma unroll
      for (int i = 0; i < 4; i++)
        af[i] = *(const f16x8*)(As[h] + (wm + i * 16 + mrow) * 32 + kq_p);
#pragma unroll
      for (int j = 0; j < JT; j++)
        bf[j] = *(const f16x8*)(Bs[h] + (wn + j * 16 + mrow) * 32 + kq_p);
#pragma unroll
      for (int i = 0; i < 4; i++)
#pragma unroll
        for (int j = 0; j < JT; j++)
          acc[i][j] = __builtin_amdgcn_mfma_f32_16x16x32_f16(af[i], bf[j], acc[i][j], 0, 0, 0);
    }
  }

  if (NORMS && MT == 128) {
    if (row0 < RQ + RK) {   // block-uniform: q or k rows
      float sums[4][4];
#pragma unroll
      for (int i = 0; i < 4; i++)
#pragma unroll
        for (int r = 0; r < 4; r++) {
          float s = 0.f;
#pragma unroll
          for (int j = 0; j < JT; j++) s += acc[i][j][r] * acc[i][j][r];
          sums[i][r] = s;
        }
#pragma unroll
      for (int off = 1; off < 16; off <<= 1)
#pragma unroll
        for (int i = 0; i < 4; i++)
#pragma unroll
          for (int r = 0; r < 4; r++)
            sums[i][r] += __shfl_xor(sums[i][r], off);
#pragma unroll
      for (int i = 0; i < 4; i++)
#pragma unroll
        for (int r = 0; r < 4; r++) {
          const float inv = rsqrtf(sums[i][r]);
#pragma unroll
          for (int j = 0; j < JT; j++) acc[i][j][r] *= inv;
        }
    }
  }

  // epilogue: C/D layout col=lane&15, row=(lane>>4)*4+reg
  const int ccol = lane & 15;
  const int crow = (lane >> 4) * 4;
  if (OUT_F16) {
    f16* C = (f16*)Cout;
#pragma unroll
    for (int j = 0; j < JT; j++) {
      const int col = col0 + wn + j * 16 + ccol;
#pragma unroll
      for (int i = 0; i < 4; i++) {
        f16* Cp = C + (size_t)(row0 + wm + i * 16 + crow) * DIM + col;
#pragma unroll
        for (int r = 0; r < 4; r++) Cp[(size_t)r * DIM] = (f16)acc[i][j][r];
      }
    }
  } else {
    float* C = (float*)Cout;
#pragma unroll
    for (int j = 0; j < JT; j++) {
      const int col = col0 + wn + j * 16 + ccol;
      float bv = BIAS ? bias[col] : 0.f;
#pragma unroll
      for (int i = 0; i < 4; i++) {
        float* Cp = C + (size_t)(row0 + wm + i * 16 + crow) * DIM + col;
#pragma unroll
        for (int r = 0; r < 4; r++) Cp[(size_t)r * DIM] = acc[i][j][r] + bv;
      }
    }
  }
}

// ---------------------------------------------------------------------------
// K3: per-(slice,b,h) partial S = sum over 256 m of g_k[m] outer f_v[m].
// Register-only outer product: each wave owns 64 m-rows independently
// (no LDS, no in-loop barriers). 8x8 fp32 acc per lane
// (d1=(lane&7)*8, d2=((lane>>3)&7)*8). Single end-of-block LDS reduction
// across the 4 waves -> one fp32 partial slice per block.
// ---------------------------------------------------------------------------
__global__ void __launch_bounds__(256) s_kernel(
    const f16* __restrict__ f, float* __restrict__ S4) {
  const int bh = blockIdx.x;
  const int b = bh >> 4, h = bh & 15;
  const int wid = threadIdx.x >> 6, lane = threadIdx.x & 63;
  const int m0 = blockIdx.y * (SEQK / NSLC) + wid * 64;
  const int d1 = (lane & 7) * 8;
  const int d2 = ((lane >> 3) & 7) * 8;
  const f16* kb = f + ((size_t)RQ + (size_t)b * SEQK + m0) * DIM + h * DH + d1;
  const f16* vb = f + ((size_t)RQ + RK + (size_t)b * SEQK + m0) * DIM + h * DH + d2;

  float acc[8][8];
#pragma unroll
  for (int i = 0; i < 8; i++)
#pragma unroll
    for (int j = 0; j < 8; j++) acc[i][j] = 0.f;

#pragma unroll 4
  for (int m = 0; m < 64; ++m) {
    f16x8 kf = *(const f16x8*)(kb + (size_t)m * DIM);
    f16x8 vf = *(const f16x8*)(vb + (size_t)m * DIM);
    float kx[8], vx[8];
#pragma unroll
    for (int e = 0; e < 8; e++) { kx[e] = (float)kf[e]; vx[e] = (float)vf[e]; }
#pragma unroll
    for (int i = 0; i < 8; i++)
#pragma unroll
      for (int j = 0; j < 8; j++)
        acc[i][j] = fmaf(kx[i], vx[j], acc[i][j]);
  }

  // cross-wave reduction (single barrier)
  __shared__ float Sacc[4][64][68];
#pragma unroll
  for (int i = 0; i < 8; i++) {
    *(float4*)&Sacc[wid][d1 + i][d2]     = *(float4*)&acc[i][0];
    *(float4*)&Sacc[wid][d1 + i][d2 + 4] = *(float4*)&acc[i][4];
  }
  __syncthreads();
  const int t = threadIdx.x;
  const int r = t >> 2, c0 = (t & 3) * 16;
  float* Sp = S4 + ((size_t)blockIdx.y * BH + bh) * (DH * DH) + r * DH + c0;
#pragma unroll
  for (int c4 = 0; c4 < 4; c4++) {
    float4 s = {0.f, 0.f, 0.f, 0.f};
#pragma unroll
    for (int w = 0; w < 4; w++) {
      float4 p = *(const float4*)&Sacc[w][r][c0 + 4 * c4];
      s.x += p.x; s.y += p.y; s.z += p.z; s.w += p.w;
    }
    *(float4*)(Sp + 4 * c4) = s;
  }
}

// ---------------------------------------------------------------------------
// K3b: sum the NSLC partial S slices -> Sh fp16 [bh][d1][d2] row-major.
// ---------------------------------------------------------------------------
__global__ void __launch_bounds__(256) s_reduce(
    const float* __restrict__ S4, f16* __restrict__ Sh) {
  const int bh = blockIdx.x;
  const int t = threadIdx.x;
  const size_t base = (size_t)bh * DH * DH + t * 16;
  constexpr size_t STR = (size_t)BH * DH * DH;
#pragma unroll
  for (int c = 0; c < 4; c++) {
    float4 s = {0.f, 0.f, 0.f, 0.f};
#pragma unroll
    for (int p = 0; p < NSLC; p++) {
      float4 sp = *(const float4*)(S4 + base + p * STR + 4 * c);
      s.x += sp.x; s.y += sp.y; s.z += sp.z; s.w += sp.w;
    }
    union { f16 h[4]; uint2 u; } o;
    o.h[0] = (f16)s.x; o.h[1] = (f16)s.y; o.h[2] = (f16)s.z; o.h[3] = (f16)s.w;
    *(uint2*)(Sh + base + 4 * c) = o.u;
  }
}

// ---------------------------------------------------------------------------
// K3c: Mt[b][n][64h+d1] = sum_d2 wt_out[n][64h+d2] * Sh[b,h][d1][d2]
// grid (8 n-blocks, 64 bh). Single K pass (K=64), MFMA.
// ---------------------------------------------------------------------------
__global__ void __launch_bounds__(256) m_build(
    const f16* __restrict__ wt_out, const f16* __restrict__ Sh,
    f16* __restrict__ Mt) {
  const int n0 = blockIdx.x * 128;
  const int bh = blockIdx.y;
  const int b = bh >> 4, h = bh & 15;
  __shared__ f16 As[128 * 64];
  __shared__ f16 Bs[64 * 64];
  const int t = threadIdx.x;
  const int wid = t >> 6, lane = t & 63;

  const f16* gA = wt_out + (size_t)(n0 + 32 * wid + (lane >> 3)) * DIM
                  + 64 * h + (lane & 7) * 8;
  f16* lA = As + 32 * wid * 64;
  const f16* gB = Sh + (size_t)bh * DH * DH + (16 * wid + (lane >> 3)) * 64
                  + (lane & 7) * 8;
  f16* lB = Bs + 16 * wid * 64;
#pragma unroll
  for (int o = 0; o < 4; o++) async16(gA + (size_t)(8 * o) * DIM, lA + 8 * o * 64);
  async16(gB, lB);
  async16(gB + 8 * 64, lB + 8 * 64);
  __syncthreads();

  const int wm = (wid >> 1) * 64;
  const int wn = (wid & 1) * 32;
  const int mrow = lane & 15;
  f32x4 acc[4][2];
#pragma unroll
  for (int i = 0; i < 4; i++)
#pragma unroll
    for (int j = 0; j < 2; j++) acc[i][j] = (f32x4){0.f, 0.f, 0.f, 0.f};

#pragma unroll
  for (int kh = 0; kh < 2; kh++) {
    const int kq = kh * 32 + (lane >> 4) * 8;
    f16x8 af[4], bf[2];
#pragma unroll
    for (int i = 0; i < 4; i++)
      af[i] = *(const f16x8*)(As + (wm + i * 16 + mrow) * 64 + kq);
#pragma unroll
    for (int j = 0; j < 2; j++)
      bf[j] = *(const f16x8*)(Bs + (wn + j * 16 + mrow) * 64 + kq);
#pragma unroll
    for (int i = 0; i < 4; i++)
#pragma unroll
      for (int j = 0; j < 2; j++)
        acc[i][j] = __builtin_amdgcn_mfma_f32_16x16x32_f16(af[i], bf[j], acc[i][j], 0, 0, 0);
  }

  const int ccol = lane & 15;
  const int crow = (lane >> 4) * 4;
  f16* Mb = Mt + (size_t)b * DIM * DIM;
#pragma unroll
  for (int j = 0; j < 2; j++) {
    const int col = 64 * h + wn + j * 16 + ccol;
#pragma unroll
    for (int i = 0; i < 4; i++) {
      f16* Mp = Mb + (size_t)(n0 + wm + i * 16 + crow) * DIM + col;
#pragma unroll
      for (int r = 0; r < 4; r++) Mp[(size_t)r * DIM] = (f16)acc[i][j][r];
    }
  }
}

// ---------------------------------------------------------------------------
extern "C" void kernel_launch(void* const* d_in, const int* in_sizes, int n_in,
                              void* d_out, int out_size, void* d_ws, size_t ws_size,
                              hipStream_t stream) {
  const float* q     = (const float*)d_in[0];
  const float* k     = (const float*)d_in[1];
  const float* v     = (const float*)d_in[2];
  const float* gamma = (const float*)d_in[3];
  const float* beta  = (const float*)d_in[4];
  const float* W_in  = (const float*)d_in[5];
  const float* W_out = (const float*)d_in[6];
  const float* b_out = (const float*)d_in[7];
  float* out = (float*)d_out;

  // workspace layout
  char* w = (char*)d_ws;
  f16*   f      = (f16*)w;                                     // 40 MB
  f16*   a_h    = f + (size_t)RTOT * DIM;                      // 40 MB
  f16*   wt_in  = a_h + (size_t)RTOT * DIM;                    // 2 MB
  f16*   wt_out = wt_in + (size_t)DIM * DIM;                   // 2 MB
  f16*   Mt     = wt_out + (size_t)DIM * DIM;                  // 8 MB
  f16*   Sh     = Mt + (size_t)BATCH * DIM * DIM;              // 512 KB
  float* S4     = (float*)(Sh + (size_t)BH * DH * DH);         // 8 MB

  // LN of q/k/v + weight transposes in one dispatch
  prep_kernel<<<RTOT / 4 + 2048, 256, 0, stream>>>(
      q, k, v, gamma, beta, a_h, W_in, W_out, wt_in, wt_out);

  // f = LN(t) @ W_in for all rows; q/k rows pre-normalized per head
  mfma_gemm<128, true, true, false, false>
      <<<dim3(RTOT / 128, DIM / 128), 256, 0, stream>>>(a_h, wt_in, f, nullptr);

  s_kernel<<<dim3(BH, NSLC), 256, 0, stream>>>(f, S4);

  s_reduce<<<BH, 256, 0, stream>>>(S4, Sh);

  m_build<<<dim3(DIM / 128, BH), 256, 0, stream>>>(wt_out, Sh, Mt);

  // out = g_q @ Mt[b]^T + b_out (per-batch weights)
  mfma_gemm<64, false, false, true, true>
      <<<dim3(RQ / 64, DIM / 128), 256, 0, stream>>>(f, Mt, out, b_out);
}